// Round 10
// baseline (394.395 us; speedup 1.0000x reference)
//
#include <hip/hip_runtime.h>
#include <cstdint>
#include <cstddef>

// VQ-VAE quantization forward, MI355X/gfx950 — bf16 split-precision MFMA version.
// dot(x, e_norm) = xh*eh + xh*el + xl*eh  (3x mfma_f32_16x16x32_bf16, fp32 accum)
//
// v10: BARRIER-FREE wave-autonomous loop + 3 blocks/CU.
//  Nine rounds showed the wall is latency exposure at ~1 wave/SIMD with in-loop
//  barriers (v6 98us best; pipelining variants v7/v9 regressed). v10 removes ALL
//  intra-loop synchronization and triples per-SIMD wave count:
//  - grid 800 x 256 thr (4 waves), 32 rows/block (25600 = 800*32 exact balance).
//  - wave w: codes [w*64,+64) x all 32 rows x full K. Private 8KB B slice
//    (single buffer; WAR via own lgkmcnt(0) before re-stage). NO s_barrier.
//  - A-frags converted in registers per wave (no shared X buffer, no ds_write);
//    4x conv redundancy absorbed by L1 + idle VALU.
//  - one vmcnt(0)/chunk (1-deep prefetch of B-DMA + x loads).
//  - LDS 32KB, acc 32 VGPR -> launch_bounds(256,3): 3 blocks/CU = 12 waves/CU.
//  - epilogue arrays alias wave-0's B slice after drain; ticket-folded finals.

typedef __attribute__((ext_vector_type(8))) short short8;
typedef __attribute__((ext_vector_type(4))) float f32x4;

namespace {
constexpr int kNT = 25600;           // N*T rows
constexpr int kD  = 1024;            // feature dim
constexpr int kM  = 256;             // codebook size
constexpr int kRPB = 32;             // rows per block
constexpr size_t kQElems = (size_t)kNT * kD;

// ws layout (float units). Codebook images: 32 chunks x [n=256][k=32] bf16,
// 16B sub-blocks swizzled: element idx = c*8192 + n*32 + (g ^ ((n>>1)&3))*8 + (k&7)
constexpr int WS_IMG_H = 0;                    // 262144 ushort = 131072 floats
constexpr int WS_IMG_L = 131072;               // 262144 ushort
constexpr int WS_E2N   = 262144;               // ||e_norm||^2 (256)
constexpr int WS_SCL   = WS_E2N + kM;          // ||e_raw|| + 1e-4 (256)
constexpr int WS_E2R   = WS_SCL + kM;          // ||e_raw||^2 (256)
constexpr int WS_COM   = WS_E2R + kM;          // commitment accumulator (4 floats)
constexpr int WS_HIST  = WS_COM + 4;           // histogram 256 ints
constexpr int WS_TICKET = WS_HIST + kM;        // last-block ticket (1 int)
}

typedef __attribute__((address_space(3))) unsigned int        lds_u32;
typedef const __attribute__((address_space(1))) unsigned int  glb_u32;
typedef const __attribute__((address_space(3))) char          lds_chc;

__device__ __forceinline__ void gl2lds16(const void* g, void* l) {
  __builtin_amdgcn_global_load_lds((glb_u32*)g, (lds_u32*)l, 16, 0, 0);
}

// inline-asm LDS read: compile-time offset immediate (16-bit unsigned);
// lgkmcnt counted manually (rule #18: counted wait + sched_barrier(0)).
template <int OFF>
__device__ __forceinline__ short8 ldsr(lds_chc* p) {
  static_assert(OFF >= 0 && OFF < 65536, "ds offset immediate");
  short8 r;
  asm volatile("ds_read_b128 %0, %1 offset:%c2" : "=v"(r) : "v"(p), "i"(OFF));
  return r;
}
// asm global load: keeps x-loads out of the compiler's vmcnt bookkeeping so our
// counted waits stay exact.
__device__ __forceinline__ f32x4 gld4(const float* p) {
  f32x4 r;
  asm volatile("global_load_dwordx4 %0, %1, off" : "=v"(r) : "v"(p));
  return r;
}

// ---------------- kernel 1: normalize codebook -> swizzled bf16 hi/lo images + stats ----
__global__ __launch_bounds__(256) void vq_normalize(const float* __restrict__ emb,
                                                    float* __restrict__ ws) {
  const int m = blockIdx.x;
  const int t = threadIdx.x;

  // zero-init stats (replaces hipMemsetAsync dispatch)
  if (t == 0) ((int*)(ws + WS_HIST))[m] = 0;
  if (m == 0 && t < 4) ws[WS_COM + t] = 0.0f;
  if (m == 0 && t == 4) ((int*)(ws + WS_TICKET))[0] = 0;

  const float4 v = reinterpret_cast<const float4*>(emb + (size_t)m * kD)[t];
  float s = v.x * v.x + v.y * v.y + v.z * v.z + v.w * v.w;
#pragma unroll
  for (int mask = 32; mask >= 1; mask >>= 1) s += __shfl_xor(s, mask);
  __shared__ float red[4];
  if ((t & 63) == 0) red[t >> 6] = s;
  __syncthreads();
  const float tot = red[0] + red[1] + red[2] + red[3];
  const float sc  = sqrtf(tot) + 1e-4f;
  const float inv = 1.0f / sc;
  const float4 nv = make_float4(v.x * inv, v.y * inv, v.z * inv, v.w * inv);

  float s2 = nv.x * nv.x + nv.y * nv.y + nv.z * nv.z + nv.w * nv.w;
#pragma unroll
  for (int mask = 32; mask >= 1; mask >>= 1) s2 += __shfl_xor(s2, mask);
  __syncthreads();
  if ((t & 63) == 0) red[t >> 6] = s2;
  __syncthreads();
  if (t == 0) {
    ws[WS_E2N + m] = red[0] + red[1] + red[2] + red[3];
    ws[WS_SCL + m] = sc;
    ws[WS_E2R + m] = tot;
  }

  // hi/lo truncation split, packed to the swizzled image
  unsigned short* imgh = (unsigned short*)(ws + WS_IMG_H);
  unsigned short* imgl = (unsigned short*)(ws + WS_IMG_L);
  const int c  = t >> 3;              // k-chunk (k = 4t..4t+3)
  const int g  = (t >> 1) & 3;        // 8-elem group within chunk
  const int sq = g ^ ((m >> 1) & 3);  // bank swizzle
  const int base = c * 8192 + m * 32 + sq * 8 + 4 * (t & 1);
  ushort4 hq, lq;
#pragma unroll
  for (int j = 0; j < 4; ++j) {
    const float fv = (&nv.x)[j];
    const unsigned int b = __float_as_uint(fv);
    const unsigned short hi = (unsigned short)(b >> 16);
    const float lof = fv - __uint_as_float(b & 0xFFFF0000u);
    const unsigned short lo = (unsigned short)(__float_as_uint(lof) >> 16);
    (&hq.x)[j] = hi; (&lq.x)[j] = lo;
  }
  *(ushort4*)(imgh + base) = hq;
  *(ushort4*)(imgl + base) = lq;
}

// ---------------- kernel 2: MFMA distances + argmin + gather + stats + finals ----
// LDS: pool[32768) = 4 wave-private B slices (w*8192 = [hi 4K][lo 4K]).
// Epilogue aliases pool[0..1536) (wave-0 slice) after loop drain + sync.

// stage wave's own 8KB B slice (its 64 codes, hi+lo) for chunk KCN
#define DMASTAGE(KCN)                                                          \
  {                                                                            \
    const unsigned short* gh_ = imgH + ((size_t)(KCN) << 13) + (w << 11) + (l << 3); \
    const unsigned short* gl_ = imgL + ((size_t)(KCN) << 13) + (w << 11) + (l << 3); \
    char* dg_ = pool + w * 8192;                                               \
    gl2lds16(gh_,        dg_);                                                 \
    gl2lds16(gh_ +  512, dg_ + 1024);                                          \
    gl2lds16(gh_ + 1024, dg_ + 2048);                                          \
    gl2lds16(gh_ + 1536, dg_ + 3072);                                          \
    gl2lds16(gl_,        dg_ + 4096);                                          \
    gl2lds16(gl_ +  512, dg_ + 5120);                                          \
    gl2lds16(gl_ + 1024, dg_ + 6144);                                          \
    gl2lds16(gl_ + 1536, dg_ + 7168);                                          \
  }

// split 8 consecutive k floats (f32x4 pair) into hi/lo bf16 frags; accumulate X2V
#define CONV8(F0, F1, AH, AL, X2V)                                             \
  {                                                                            \
    union { short8 v; unsigned short u[8]; } H_, L_;                           \
    _Pragma("unroll")                                                          \
    for (int jj_ = 0; jj_ < 8; ++jj_) {                                        \
      const float fv_ = (jj_ < 4) ? (F0)[jj_] : (F1)[jj_ - 4];                 \
      const unsigned int b_ = __float_as_uint(fv_);                            \
      H_.u[jj_] = (unsigned short)(b_ >> 16);                                  \
      const float lo_ = fv_ - __uint_as_float(b_ & 0xFFFF0000u);               \
      L_.u[jj_] = (unsigned short)(__float_as_uint(lo_) >> 16);                \
      X2V += fv_ * fv_;                                                        \
    }                                                                          \
    AH = H_.v; AL = L_.v;                                                      \
  }

#define MM4(AR, B0, B1, B2, B3, RT)                                                        \
  acc[RT][0] = __builtin_amdgcn_mfma_f32_16x16x32_bf16(AR, B0, acc[RT][0], 0, 0, 0);       \
  acc[RT][1] = __builtin_amdgcn_mfma_f32_16x16x32_bf16(AR, B1, acc[RT][1], 0, 0, 0);       \
  acc[RT][2] = __builtin_amdgcn_mfma_f32_16x16x32_bf16(AR, B2, acc[RT][2], 0, 0, 0);       \
  acc[RT][3] = __builtin_amdgcn_mfma_f32_16x16x32_bf16(AR, B3, acc[RT][3], 0, 0, 0);

__global__ __launch_bounds__(256, 3) void vq_main(const float* __restrict__ x,
                                                  const float* __restrict__ emb,
                                                  const float* __restrict__ wsc,
                                                  float* __restrict__ out,
                                                  float* __restrict__ commit_sum,
                                                  int* __restrict__ hist,
                                                  int* __restrict__ ticket) {
  __shared__ char pool[32768];     // 4 x 8KB wave-private B slices; 3 blocks/CU

  const int t   = threadIdx.x;
  const int l   = t & 63;
  const int w   = t >> 6;          // 0..3 (code quarter)
  const int nlo = l & 15;
  const int kq  = l >> 4;          // 0..3
  const int blk0 = blockIdx.x * kRPB;

  const unsigned short* imgH = (const unsigned short*)(wsc + WS_IMG_H);
  const unsigned short* imgL = (const unsigned short*)(wsc + WS_IMG_L);

  // x row pointers: lane (nlo,kq) -> rows nlo (rt0) and 16+nlo (rt1), k = kq*8
  const float* xr0 = x + (size_t)(blk0 + nlo) * kD + kq * 8;
  const float* xr1 = xr0 + (size_t)16 * kD;

  // B-frag lane base — v2/v6's measured-conflict-free [64][32] tile pattern
  const int sqz = kq ^ ((nlo >> 1) & 3);
  lds_chc* pB = (lds_chc*)pool + w * 8192 + nlo * 64 + sqz * 16;

  f32x4 acc[2][4];
#pragma unroll
  for (int i = 0; i < 2; ++i)
#pragma unroll
    for (int j = 0; j < 4; ++j) acc[i][j] = (f32x4)0.0f;
  float x2a = 0.0f, x2b = 0.0f;

  // ---- prologue: DMA B(0) then x(0). Entering iter c: outstanding =
  // [DMA(c) (8, older), x(c) (4, newer)] — drained by the in-iter vmcnt(0).
  DMASTAGE(0)
  f32x4 xv0 = gld4(xr0);
  f32x4 xv1 = gld4(xr0 + 4);
  f32x4 xv2 = gld4(xr1);
  f32x4 xv3 = gld4(xr1 + 4);

#pragma unroll 1
  for (int c = 0; c < 32; ++c) {
    asm volatile("s_waitcnt vmcnt(0)" ::: "memory");   // B(c) in LDS, x(c) in regs
    __builtin_amdgcn_sched_barrier(0);
    // B fragments (8 x ds_read_b128 from own slice)
    short8 bh0 = ldsr<0>(pB),    bh1 = ldsr<1024>(pB);
    short8 bh2 = ldsr<2048>(pB), bh3 = ldsr<3072>(pB);
    short8 bl0 = ldsr<4096>(pB), bl1 = ldsr<5120>(pB);
    short8 bl2 = ldsr<6144>(pB), bl3 = ldsr<7168>(pB);
    // A fragments: convert x(c) in registers (overlaps LDS latency)
    short8 ah0, al0, ah1, al1;
    CONV8(xv0, xv1, ah0, al0, x2a)
    CONV8(xv2, xv3, ah1, al1, x2b)
    asm volatile("s_waitcnt lgkmcnt(0)" ::: "memory"); // B frags in regs
    __builtin_amdgcn_sched_barrier(0);
    // re-stage own slice for c+1 (safe: own reads retired), then x(c+1)
    const int cn = (c < 31) ? c + 1 : 31;
    DMASTAGE(cn)
    {
      const float* xp0 = xr0 + cn * 32;
      const float* xp1 = xr1 + cn * 32;
      xv0 = gld4(xp0); xv1 = gld4(xp0 + 4);
      xv2 = gld4(xp1); xv3 = gld4(xp1 + 4);
    }
    // 24 MFMAs: 3-term split, round-robin ct (dep distance >= 4)
    __builtin_amdgcn_s_setprio(1);
    MM4(ah0, bh0, bh1, bh2, bh3, 0)
    MM4(ah1, bh0, bh1, bh2, bh3, 1)
    MM4(ah0, bl0, bl1, bl2, bl3, 0)
    MM4(ah1, bl0, bl1, bl2, bl3, 1)
    MM4(al0, bh0, bh1, bh2, bh3, 0)
    MM4(al1, bh0, bh1, bh2, bh3, 1)
    __builtin_amdgcn_s_setprio(0);
  }

  // ---- drain all asm-issued VMEM before register reuse / LDS alias (v5 lesson).
  asm volatile("s_waitcnt vmcnt(0)"
               :: "v"(xv0), "v"(xv1), "v"(xv2), "v"(xv3) : "memory");

  // ---- ||x_row||^2: reduce over kq; lanes with same nlo hold row totals
  x2a += __shfl_xor(x2a, 16); x2a += __shfl_xor(x2a, 32);  // row nlo
  x2b += __shfl_xor(x2b, 16); x2b += __shfl_xor(x2b, 32);  // row 16+nlo

  // ---- per-wave argmin over its 64 codes.
  // acc[rt][ct][rg] at lane (nlo,kq) = dot(row rt*16+kq*4+rg, code w*64+ct*16+nlo)
  float eN[4];
#pragma unroll
  for (int ct = 0; ct < 4; ++ct) eN[ct] = wsc[WS_E2N + w * 64 + ct * 16 + nlo];

  float bv[2][4]; int bj[2][4];        // [rt][rg]
#pragma unroll
  for (int rt = 0; rt < 2; ++rt)
#pragma unroll
    for (int rg = 0; rg < 4; ++rg) { bv[rt][rg] = 3.0e38f; bj[rt][rg] = 0; }
#pragma unroll
  for (int ct = 0; ct < 4; ++ct) {
    const int j = w * 64 + ct * 16 + nlo;
#pragma unroll
    for (int rt = 0; rt < 2; ++rt)
#pragma unroll
      for (int rg = 0; rg < 4; ++rg) {
        const float v = eN[ct] - 2.0f * acc[rt][ct][rg];
        if (v < bv[rt][rg] || (v == bv[rt][rg] && j < bj[rt][rg])) {
          bv[rt][rg] = v; bj[rt][rg] = j;
        }
      }
  }
#pragma unroll
  for (int mk = 1; mk <= 8; mk <<= 1) {   // butterfly across nlo (16-group)
#pragma unroll
    for (int rt = 0; rt < 2; ++rt)
#pragma unroll
      for (int rg = 0; rg < 4; ++rg) {
        const float ov = __shfl_xor(bv[rt][rg], mk);
        const int   oj = __shfl_xor(bj[rt][rg], mk);
        if (ov < bv[rt][rg] || (ov == bv[rt][rg] && oj < bj[rt][rg])) {
          bv[rt][rg] = ov; bj[rt][rg] = oj;
        }
      }
  }

  // epilogue aliases in wave-0's slice (all waves past their loop after sync)
  float* x2s  = (float*)pool;              // 32 f   @0
  float* bvp  = x2s + kRPB;                // 4*32 f @128
  int*   bjp  = (int*)(bvp + 4 * kRPB);    // 4*32 i @640
  int*   idxs = bjp + 4 * kRPB;            // 32 i   @1152
  float* red  = (float*)(idxs + kRPB);     // 4 f    @1280
  int*   doneflag = (int*)(red + 4);       //        @1296

  __syncthreads();   // all waves finished loop + drain
  if (w == 0 && l < 16) { x2s[l] = x2a; x2s[16 + l] = x2b; }
  if (nlo == 0) {
#pragma unroll
    for (int rt = 0; rt < 2; ++rt)
#pragma unroll
      for (int rg = 0; rg < 4; ++rg) {
        const int row = rt * 16 + kq * 4 + rg;
        bvp[w * kRPB + row] = bv[rt][rg];
        bjp[w * kRPB + row] = bj[rt][rg];
      }
  }
  __syncthreads();

  // ---- combine across waves + stats (wave 0)
  if (w == 0) {
    float cl = 0.0f;
    if (l < kRPB) {
      const int row = l;
      float v = bvp[row]; int j = bjp[row];
#pragma unroll
      for (int wv = 1; wv < 4; ++wv) {
        const float v2 = bvp[wv * kRPB + row]; const int j2 = bjp[wv * kRPB + row];
        if (v2 < v || (v2 == v && j2 < j)) { v = v2; j = j2; }
      }
      idxs[row] = j;
      atomicAdd(&hist[j], 1);
      // ||x - e_raw||^2 = ||x||^2 + ||e_raw||^2 - (e2n - v)*scl  [(e2n-v) = 2*dot]
      cl = x2s[row] + wsc[WS_E2R + j] - (wsc[WS_E2N + j] - v) * wsc[WS_SCL + j];
    }
#pragma unroll
    for (int mk = 1; mk <= 32; mk <<= 1) cl += __shfl_xor(cl, mk);
    if (l == 0) atomicAdd(commit_sum, cl);
  }
  __syncthreads();

  // ---- gather: quantized row = raw embedding[argmin]; wave w -> rows w*8..+8
  const float4* emb4 = (const float4*)emb;
  float4* out4 = (float4*)out;
#pragma unroll
  for (int rr = 0; rr < 8; ++rr) {
    const int row = w * 8 + rr;
    const int j = idxs[row];
    const float4* s = emb4 + (size_t)j * (kD / 4);
    float4* d = out4 + (size_t)(blk0 + row) * (kD / 4);
#pragma unroll
    for (int cc = 0; cc < 4; ++cc) d[cc * 64 + l] = s[cc * 64 + l];
  }

  // ---- last-finishing block computes the final scalars (folds vq_final)
  __threadfence();
  if (t == 0) *doneflag = atomicAdd(ticket, 1);
  __syncthreads();
  if (*doneflag == (kNT / kRPB) - 1) {
    const int h = atomicAdd(&hist[t], 0);          // read via atomic path
    const float p = (float)h * (1.0f / (float)kNT);
    float s = p * logf(p + 1e-10f);
#pragma unroll
    for (int mask = 32; mask >= 1; mask >>= 1) s += __shfl_xor(s, mask);
    if ((t & 63) == 0) red[t >> 6] = s;
    __syncthreads();
    if (t == 0) {
      const float ent = red[0] + red[1] + red[2] + red[3];
      const float cs = atomicAdd(commit_sum, 0.0f);
      out[kQElems]     = cs * (1.0f / (float)kQElems);
      out[kQElems + 1] = expf(-ent);
    }
  }
}

extern "C" void kernel_launch(void* const* d_in, const int* in_sizes, int n_in,
                              void* d_out, int out_size, void* d_ws, size_t ws_size,
                              hipStream_t stream) {
  (void)in_sizes; (void)n_in; (void)out_size; (void)ws_size;
  const float* x   = (const float*)d_in[0];
  const float* emb = (const float*)d_in[1];
  float* out = (float*)d_out;
  float* ws  = (float*)d_ws;

  hipLaunchKernelGGL(vq_normalize, dim3(kM), dim3(256), 0, stream, emb, ws);
  hipLaunchKernelGGL(vq_main, dim3(kNT / kRPB), dim3(256), 0, stream,
                     x, emb, ws, out, ws + WS_COM, (int*)(ws + WS_HIST),
                     (int*)(ws + WS_TICKET));
}